// Round 6
// baseline (201.600 us; speedup 1.0000x reference)
//
#include <hip/hip_runtime.h>

#define N_NODES 100000
#define B_TOTAL 50000
#define NSAMP   16
#define FDIM    256
#define KDIM    512    // 2*FDIM
#define EDIM    256
#define EP      512    // stacked output dim e' : [0,256)=W1 rows, [256,512)=W2 rows
#define NPB     128    // nodes per pgemm block
#define NP_PAD  100096 // N_NODES rounded to NPB
#define NPBLK   (NP_PAD / NPB)               // 782
#define NBC     32     // batch rows per combine block
#define NBLKC   ((B_TOTAL + NBC - 1) / NBC)  // 1563

// ws layout: Wcat image [kc=4][512 e'][128B swizzled] = 256KB, then
// H image [NP_PAD][512] bf16 = 102.5MB.
#define WIMG_SZ  (4 * 65536)
#define HIMG_OFF ((size_t)WIMG_SZ)
#define HIMG_SZ  ((size_t)NP_PAD * EP * 2)

typedef __attribute__((ext_vector_type(4))) float float4v;
typedef __attribute__((ext_vector_type(4))) short short4v;
typedef __attribute__((ext_vector_type(8))) short short8v;
typedef __attribute__((ext_vector_type(2))) unsigned int uint2v;

__device__ __forceinline__ unsigned short f2bf(float f) {
  unsigned int u = __builtin_bit_cast(unsigned int, f);
  u += 0x7FFFu + ((u >> 16) & 1u);   // round-to-nearest-even
  return (unsigned short)(u >> 16);
}

__device__ __forceinline__ short4v pack4(float4v v) {
  short4v r;
  r[0] = (short)f2bf(v[0]);
  r[1] = (short)f2bf(v[1]);
  r[2] = (short)f2bf(v[2]);
  r[3] = (short)f2bf(v[3]);
  return r;
}

__device__ __forceinline__ uint2v pack4u(float4v v) {
  unsigned int lo = ((unsigned)f2bf(v[1]) << 16) | f2bf(v[0]);
  unsigned int hi = ((unsigned)f2bf(v[3]) << 16) | f2bf(v[2]);
  uint2v r; r[0] = lo; r[1] = hi;
  return r;
}

__device__ __forceinline__ float4v bf4_to_f32(uint2v u) {
  float4v r;
  r[0] = __builtin_bit_cast(float, u[0] << 16);
  r[1] = __builtin_bit_cast(float, u[0] & 0xffff0000u);
  r[2] = __builtin_bit_cast(float, u[1] << 16);
  r[3] = __builtin_bit_cast(float, u[1] & 0xffff0000u);
  return r;
}

// Inline-asm 8B load: compiler cannot serialize these; we wait manually.
__device__ __forceinline__ uint2v ld8(const void* p) {
  uint2v r;
  asm volatile("global_load_dwordx2 %0, %1, off" : "=v"(r) : "v"(p) : "memory");
  return r;
}

__device__ __forceinline__ void lds_load16(const void* g, void* l) {
  __builtin_amdgcn_global_load_lds(
      (const __attribute__((address_space(1))) unsigned int*)g,
      (__attribute__((address_space(3))) unsigned int*)l, 16, 0, 0);
}

// ---------------------------------------------------------------------------
// Kernel 0: pack Wcat = [W1; W2] -> bf16 swizzled image [kc=4][512 e'][128B].
// Wcat[e'][k] = W[e'&255][k + 256*(e'>>8)], k in [0,256).
// ---------------------------------------------------------------------------
__global__ __launch_bounds__(256) void pack_wcat(
    const float* __restrict__ weight, unsigned char* __restrict__ wimg) {
  const int idx = blockIdx.x * 256 + threadIdx.x;   // 512*64 = 32768 total
  const int ep  = idx >> 6;        // 0..511
  const int k4  = idx & 63;        // float4 group within 256-k row
  const int k   = k4 * 4;
  const int kc  = k >> 6;
  const int kl  = k & 63;
  const int e   = ep & 255;
  const int ks  = k + ((ep >> 8) << 8);   // +256 for the W2 half
  float4v wv = *(const float4v*)(weight + (size_t)e * KDIM + ks);
  *(short4v*)(wimg + kc * 65536 + ep * 128 +
              (((unsigned)(kl * 2)) ^ ((unsigned)(ep & 7) << 4))) = pack4(wv);
}

// ---------------------------------------------------------------------------
// Kernel 1: projection GEMM. H[n][e'] = sum_k F[n][k] * Wcat[e'][k].
// 512 threads = 8 waves: (we 0..3 -> 128 e' rows, wn 0..1 -> 64 nodes).
// Block tile: 512 e' x 128 nodes, K=256 in 4 chunks of 64.
// F is read f32 LINEARLY (once, 100MB total) and converted in-kernel.
// LDS: W chunk 64KB (global_load_lds from pre-swizzled image) + F chunk 16KB.
// ---------------------------------------------------------------------------
__global__ __launch_bounds__(512, 2) void pgemm(
    const float* __restrict__ features,
    const unsigned char* __restrict__ wimg,
    unsigned short* __restrict__ himg) {
  __shared__ alignas(16) unsigned char lds_w[EP * 128];    // 64KB
  __shared__ alignas(16) unsigned char lds_f[NPB * 128];   // 16KB

  const int tid = threadIdx.x;
  const int l   = tid & 63;
  const int w   = tid >> 6;     // 0..7
  const int we  = w & 3;        // e' quarter (128 rows)
  const int wn  = w >> 2;       // node half (64)
  const int lr  = l & 15;
  const int g   = l >> 4;
  const int n0  = blockIdx.x * NPB;

  float4v acc[8][4];
  #pragma unroll
  for (int mi = 0; mi < 8; ++mi)
    #pragma unroll
    for (int ni = 0; ni < 4; ++ni)
      acc[mi][ni] = (float4v){0.f, 0.f, 0.f, 0.f};

  for (int kc = 0; kc < 4; ++kc) {
    __syncthreads();
    // stage W chunk (64KB) via global_load_lds from pre-swizzled image
    {
      const unsigned char* ws_ = wimg + kc * 65536;
      #pragma unroll
      for (int i = 0; i < 8; ++i)
        lds_load16(ws_ + i * 8192 + tid * 16, lds_w + i * 8192 + (w << 10));
    }
    // stage F chunk: f32 -> bf16 swizzled [128 rows][128B]
    for (int i = tid; i < NPB * 16; i += 512) {
      const int r = i >> 4;
      const int j = i & 15;
      int n = n0 + r; if (n >= N_NODES) n = 0;
      float4v fv = *(const float4v*)(features + (size_t)n * FDIM + kc * 64 + j * 4);
      *(short4v*)(lds_f + r * 128 +
                  (((unsigned)(j * 8)) ^ ((unsigned)(r & 7) << 4))) = pack4(fv);
    }
    __syncthreads();
    #pragma unroll
    for (int ks = 0; ks < 2; ++ks) {
      const int ko = ks * 32;
      short8v afr[8], bfr[4];
      #pragma unroll
      for (int mi = 0; mi < 8; ++mi) {
        const int e = we * 128 + mi * 16 + lr;
        const unsigned int sw = (unsigned)(e & 7) << 4;
        const unsigned char* base = lds_w + e * 128;
        short4v lo = *(const short4v*)(base + (((unsigned)((ko + 4 * g) * 2)) ^ sw));
        short4v hi = *(const short4v*)(base + (((unsigned)((ko + 16 + 4 * g) * 2)) ^ sw));
        afr[mi] = __builtin_shufflevector(lo, hi, 0, 1, 2, 3, 4, 5, 6, 7);
      }
      #pragma unroll
      for (int ni = 0; ni < 4; ++ni) {
        const int rn = wn * 64 + ni * 16 + lr;
        const unsigned int sw = (unsigned)(rn & 7) << 4;
        const unsigned char* base = lds_f + rn * 128;
        short4v lo = *(const short4v*)(base + (((unsigned)((ko + 4 * g) * 2)) ^ sw));
        short4v hi = *(const short4v*)(base + (((unsigned)((ko + 16 + 4 * g) * 2)) ^ sw));
        bfr[ni] = __builtin_shufflevector(lo, hi, 0, 1, 2, 3, 4, 5, 6, 7);
      }
      #pragma unroll
      for (int mi = 0; mi < 8; ++mi)
        #pragma unroll
        for (int ni = 0; ni < 4; ++ni)
          acc[mi][ni] = __builtin_amdgcn_mfma_f32_16x16x32_bf16(afr[mi], bfr[ni], acc[mi][ni], 0, 0, 0);
    }
  }

  // store H bf16: per frag, lane holds e' = e0..e0+3 (contiguous) for node n.
  #pragma unroll
  for (int ni = 0; ni < 4; ++ni) {
    const int n = n0 + wn * 64 + ni * 16 + lr;
    if (n >= N_NODES) continue;
    #pragma unroll
    for (int mi = 0; mi < 8; ++mi) {
      const int e0 = we * 128 + mi * 16 + g * 4;
      *(uint2v*)(himg + (size_t)n * EP + e0) = pack4u(acc[mi][ni]);
    }
  }
}

// ---------------------------------------------------------------------------
// Kernel 2: gather + combine + ReLU -> out.
// out[e][b] = relu( H[nodes[b]][e] + (1/16) sum_s H[neigh[b][s]][e+256] ).
// 256 threads = 4 waves x 8 rows; 17 asm loads in flight per row; LDS
// [32][257] f32 transpose tile -> coalesced 128B out writes. 33KB -> 4 blk/CU.
// ---------------------------------------------------------------------------
__global__ __launch_bounds__(256, 4) void gather_combine(
    const int* __restrict__ nodes,
    const int* __restrict__ neigh,
    const unsigned short* __restrict__ himg,
    float* __restrict__ out) {
  __shared__ float lds_t[NBC][257];

  const int tid = threadIdx.x;
  const int l   = tid & 63;
  const int w   = tid >> 6;    // 0..3
  const int b0  = blockIdx.x * NBC;

  for (int rr = 0; rr < 8; ++rr) {
    const int r  = w * 8 + rr;
    const int rb = b0 + r;
    const int rbc = rb < B_TOTAL ? rb : B_TOTAL - 1;
    const int node = nodes[rbc];
    const size_t lo4 = (size_t)l * 4;
    uint2v vs  = ld8(himg + (size_t)node * EP + lo4);
    uint2v n0v = ld8(himg + (size_t)neigh[rbc * NSAMP +  0] * EP + 256 + lo4);
    uint2v n1v = ld8(himg + (size_t)neigh[rbc * NSAMP +  1] * EP + 256 + lo4);
    uint2v n2v = ld8(himg + (size_t)neigh[rbc * NSAMP +  2] * EP + 256 + lo4);
    uint2v n3v = ld8(himg + (size_t)neigh[rbc * NSAMP +  3] * EP + 256 + lo4);
    uint2v n4v = ld8(himg + (size_t)neigh[rbc * NSAMP +  4] * EP + 256 + lo4);
    uint2v n5v = ld8(himg + (size_t)neigh[rbc * NSAMP +  5] * EP + 256 + lo4);
    uint2v n6v = ld8(himg + (size_t)neigh[rbc * NSAMP +  6] * EP + 256 + lo4);
    uint2v n7v = ld8(himg + (size_t)neigh[rbc * NSAMP +  7] * EP + 256 + lo4);
    uint2v n8v = ld8(himg + (size_t)neigh[rbc * NSAMP +  8] * EP + 256 + lo4);
    uint2v n9v = ld8(himg + (size_t)neigh[rbc * NSAMP +  9] * EP + 256 + lo4);
    uint2v nav = ld8(himg + (size_t)neigh[rbc * NSAMP + 10] * EP + 256 + lo4);
    uint2v nbv = ld8(himg + (size_t)neigh[rbc * NSAMP + 11] * EP + 256 + lo4);
    uint2v ncv = ld8(himg + (size_t)neigh[rbc * NSAMP + 12] * EP + 256 + lo4);
    uint2v ndv = ld8(himg + (size_t)neigh[rbc * NSAMP + 13] * EP + 256 + lo4);
    uint2v nev = ld8(himg + (size_t)neigh[rbc * NSAMP + 14] * EP + 256 + lo4);
    uint2v nfv = ld8(himg + (size_t)neigh[rbc * NSAMP + 15] * EP + 256 + lo4);
    asm volatile("s_waitcnt vmcnt(0)" ::: "memory");
    __builtin_amdgcn_sched_barrier(0);

    float4v a0 = bf4_to_f32(n0v) + bf4_to_f32(n1v);
    float4v a1 = bf4_to_f32(n2v) + bf4_to_f32(n3v);
    float4v a2 = bf4_to_f32(n4v) + bf4_to_f32(n5v);
    float4v a3 = bf4_to_f32(n6v) + bf4_to_f32(n7v);
    float4v a4 = bf4_to_f32(n8v) + bf4_to_f32(n9v);
    float4v a5 = bf4_to_f32(nav) + bf4_to_f32(nbv);
    float4v a6 = bf4_to_f32(ncv) + bf4_to_f32(ndv);
    float4v a7 = bf4_to_f32(nev) + bf4_to_f32(nfv);
    a0 += a1; a2 += a3; a4 += a5; a6 += a7;
    a0 += a2; a4 += a6;
    a0 += a4;
    float4v v = bf4_to_f32(vs) + a0 * 0.0625f;

    #pragma unroll
    for (int j = 0; j < 4; ++j) {
      float x = v[j];
      lds_t[r][l * 4 + j] = x > 0.f ? x : 0.f;
    }
  }

  __syncthreads();

  // transpose write: lanes 0-31 -> b, two e per instruction (256B store)
  const int lb = l & 31;
  const int he = l >> 5;
  const int b  = b0 + lb;
  #pragma unroll
  for (int t = 0; t < 32; ++t) {
    const int e = w * 64 + t * 2 + he;
    if (b < B_TOTAL)
      out[(size_t)e * B_TOTAL + b] = lds_t[lb][e];
  }
}

// ---------------------------------------------------------------------------
// Fallback (ws too small): round-1 fused kernel, known-correct.
// ---------------------------------------------------------------------------
__global__ __launch_bounds__(256, 1) void encoder_fused(
    const int* __restrict__ nodes,
    const int* __restrict__ neigh,
    const float* __restrict__ features,
    const float* __restrict__ weight,
    float* __restrict__ out) {
  __shared__ alignas(16) unsigned char lds_cmb[64 * KDIM * 2];
  __shared__ alignas(16) unsigned char lds_w[EDIM * 128 * 2];

  const int tid = threadIdx.x;
  const int l   = tid & 63;
  const int w   = tid >> 6;
  const int b0  = blockIdx.x * 64;

  for (int rr = 0; rr < 16; ++rr) {
    const int r  = w * 16 + rr;
    const int rb = b0 + r;
    unsigned char* rowp = lds_cmb + r * (KDIM * 2);
    const unsigned int sw = (unsigned)(r & 7) << 4;
    if (rb < B_TOTAL) {
      const int node = nodes[rb];
      float4v selfv = *(const float4v*)(features + (size_t)node * FDIM + l * 4);
      float4v accv = {0.f, 0.f, 0.f, 0.f};
      #pragma unroll
      for (int s = 0; s < NSAMP; ++s) {
        const int ni = neigh[rb * NSAMP + s];
        accv += *(const float4v*)(features + (size_t)ni * FDIM + l * 4);
      }
      accv *= 0.0625f;
      *(short4v*)(rowp + (((unsigned)(l * 8)) ^ sw))       = pack4(selfv);
      *(short4v*)(rowp + (((unsigned)(512 + l * 8)) ^ sw)) = pack4(accv);
    } else {
      short4v z = {0, 0, 0, 0};
      *(short4v*)(rowp + (((unsigned)(l * 8)) ^ sw))       = z;
      *(short4v*)(rowp + (((unsigned)(512 + l * 8)) ^ sw)) = z;
    }
  }

  const int lr = l & 15;
  const int g  = l >> 4;
  float4v acc[4][4];
  #pragma unroll
  for (int mi = 0; mi < 4; ++mi)
    #pragma unroll
    for (int ni = 0; ni < 4; ++ni)
      acc[mi][ni] = (float4v){0.f, 0.f, 0.f, 0.f};

  for (int kc = 0; kc < 4; ++kc) {
    __syncthreads();
    const int k0 = kc * 128;
    for (int i = tid; i < EDIM * 32; i += 256) {
      const int e  = i >> 5;
      const int kq = i & 31;
      float4v wv = *(const float4v*)(weight + (size_t)e * KDIM + k0 + kq * 4);
      *(short4v*)(lds_w + e * 256 + (((unsigned)(kq * 8)) ^ ((unsigned)(e & 7) << 4))) = pack4(wv);
    }
    __syncthreads();
    #pragma unroll
    for (int ks = 0; ks < 4; ++ks) {
      const int ko = ks * 32;
      short8v afr[4], bfr[4];
      #pragma unroll
      for (int mi = 0; mi < 4; ++mi) {
        const int e = w * 64 + mi * 16 + lr;
        const unsigned int sw = (unsigned)(e & 7) << 4;
        const unsigned char* base = lds_w + e * 256;
        short4v lo = *(const short4v*)(base + (((unsigned)((ko + 4 * g) * 2)) ^ sw));
        short4v hi = *(const short4v*)(base + (((unsigned)((ko + 16 + 4 * g) * 2)) ^ sw));
        afr[mi] = __builtin_shufflevector(lo, hi, 0, 1, 2, 3, 4, 5, 6, 7);
      }
      #pragma unroll
      for (int ni = 0; ni < 4; ++ni) {
        const int rrow = ni * 16 + lr;
        const unsigned int sw = (unsigned)(rrow & 7) << 4;
        const unsigned char* base = lds_cmb + rrow * (KDIM * 2);
        const int kk = k0 + ko;
        short4v lo = *(const short4v*)(base + (((unsigned)((kk + 4 * g) * 2)) ^ sw));
        short4v hi = *(const short4v*)(base + (((unsigned)((kk + 16 + 4 * g) * 2)) ^ sw));
        bfr[ni] = __builtin_shufflevector(lo, hi, 0, 1, 2, 3, 4, 5, 6, 7);
      }
      #pragma unroll
      for (int mi = 0; mi < 4; ++mi)
        #pragma unroll
        for (int ni = 0; ni < 4; ++ni)
          acc[mi][ni] = __builtin_amdgcn_mfma_f32_16x16x32_bf16(afr[mi], bfr[ni], acc[mi][ni], 0, 0, 0);
    }
  }

  #pragma unroll
  for (int ni = 0; ni < 4; ++ni) {
    const int b = b0 + ni * 16 + lr;
    if (b >= B_TOTAL) continue;
    #pragma unroll
    for (int mi = 0; mi < 4; ++mi) {
      const int e = w * 64 + mi * 16 + g * 4;
      #pragma unroll
      for (int q = 0; q < 4; ++q) {
        float v = acc[mi][ni][q];
        out[(size_t)(e + q) * B_TOTAL + b] = v > 0.f ? v : 0.f;
      }
    }
  }
}

extern "C" void kernel_launch(void* const* d_in, const int* in_sizes, int n_in,
                              void* d_out, int out_size, void* d_ws, size_t ws_size,
                              hipStream_t stream) {
  const int*   nodes    = (const int*)d_in[0];
  const int*   neigh    = (const int*)d_in[1];
  const float* features = (const float*)d_in[2];
  const float* weight   = (const float*)d_in[3];
  float*       out      = (float*)d_out;

  if (ws_size >= HIMG_OFF + HIMG_SZ) {
    unsigned char*  wimg = (unsigned char*)d_ws;
    unsigned short* himg = (unsigned short*)((unsigned char*)d_ws + HIMG_OFF);
    pack_wcat<<<128, 256, 0, stream>>>(weight, wimg);
    pgemm<<<NPBLK, 512, 0, stream>>>(features, wimg, himg);
    gather_combine<<<NBLKC, 256, 0, stream>>>(nodes, neigh, himg, out);
  } else {
    encoder_fused<<<(B_TOTAL + 63) / 64, 256, 0, stream>>>(nodes, neigh, features, weight, out);
  }
}

// Round 7
// 129.543 us; speedup vs baseline: 1.5562x; 1.5562x over previous
//
#include <hip/hip_runtime.h>

#define N_NODES 100000
#define B_TOTAL 50000
#define NSAMP   16
#define FDIM    256
#define KDIM    512   // 2*FDIM
#define EDIM    256
#define NBT     64    // batch columns per GEMM block
#define B_PAD   50048 // B_TOTAL rounded to NBT
#define NBLK    (B_PAD / NBT)   // 782

// X image: [blk][kc=4][rloc=64][256B swizzled]  -> 64KB per blk, 50.05MB total
#define XCHUNK  16384            // 64 rows * 256B
#define XBLK    (4 * XCHUNK)     // 65536
// W image: [kc=4][e=256][256B swizzled] -> 256KB, after X image in ws
#define WIMG_OFF ((size_t)NBLK * XBLK)
#define WIMG_SZ  (4 * 65536)
// bf16 feature image after W image
#define FB_OFF   (WIMG_OFF + WIMG_SZ)
#define FB_SZ    ((size_t)N_NODES * FDIM * 2)

#define FP_BLOCKS 12500   // N_NODES*FDIM/8/256
#define PW_BLOCKS 128

typedef __attribute__((ext_vector_type(4))) float float4v;
typedef __attribute__((ext_vector_type(4))) short short4v;
typedef __attribute__((ext_vector_type(8))) short short8v;
typedef __attribute__((ext_vector_type(2))) unsigned int uint2v;

__device__ __forceinline__ unsigned short f2bf(float f) {
  unsigned int u = __builtin_bit_cast(unsigned int, f);
  u += 0x7FFFu + ((u >> 16) & 1u);   // round-to-nearest-even
  return (unsigned short)(u >> 16);
}

__device__ __forceinline__ short4v pack4(float4v v) {
  short4v r;
  r[0] = (short)f2bf(v[0]);
  r[1] = (short)f2bf(v[1]);
  r[2] = (short)f2bf(v[2]);
  r[3] = (short)f2bf(v[3]);
  return r;
}

__device__ __forceinline__ uint2v pack4u(float4v v) {
  unsigned int lo = ((unsigned)f2bf(v[1]) << 16) | f2bf(v[0]);
  unsigned int hi = ((unsigned)f2bf(v[3]) << 16) | f2bf(v[2]);
  uint2v r; r[0] = lo; r[1] = hi;
  return r;
}

__device__ __forceinline__ float4v bf4_to_f32(uint2v u) {
  float4v r;
  r[0] = __builtin_bit_cast(float, u[0] << 16);
  r[1] = __builtin_bit_cast(float, u[0] & 0xffff0000u);
  r[2] = __builtin_bit_cast(float, u[1] << 16);
  r[3] = __builtin_bit_cast(float, u[1] & 0xffff0000u);
  return r;
}

// Inline-asm 8B load: compiler cannot serialize these; we wait manually.
__device__ __forceinline__ uint2v ld8(const void* p) {
  uint2v r;
  asm volatile("global_load_dwordx2 %0, %1, off" : "=v"(r) : "v"(p) : "memory");
  return r;
}

__device__ __forceinline__ void lds_load16(const void* g, void* l) {
  __builtin_amdgcn_global_load_lds(
      (const __attribute__((address_space(1))) unsigned int*)g,
      (__attribute__((address_space(3))) unsigned int*)l, 16, 0, 0);
}

// ---------------------------------------------------------------------------
// Kernel A: (blocks < FP_BLOCKS)  features f32 -> bf16 image, NT loads so the
// 102MB f32 stream doesn't evict the bf16 table we're writing into L3.
//           (blocks >= FP_BLOCKS) pack W -> bf16 swizzled image.
// ---------------------------------------------------------------------------
__global__ __launch_bounds__(256) void prep_pack(
    const float* __restrict__ f, unsigned short* __restrict__ o,
    const float* __restrict__ weight, unsigned char* __restrict__ wimg) {
  if (blockIdx.x < FP_BLOCKS) {
    const size_t i = ((size_t)blockIdx.x * 256 + threadIdx.x) * 8;
    float4v a = __builtin_nontemporal_load((const float4v*)(f + i));
    float4v b = __builtin_nontemporal_load((const float4v*)(f + i + 4));
    short4v ra = pack4(a), rb = pack4(b);
    short8v r;
    r[0]=ra[0]; r[1]=ra[1]; r[2]=ra[2]; r[3]=ra[3];
    r[4]=rb[0]; r[5]=rb[1]; r[6]=rb[2]; r[7]=rb[3];
    *(short8v*)(o + i) = r;   // regular store: keep fb resident in L3
  } else {
    const int idx = (blockIdx.x - FP_BLOCKS) * 256 + threadIdx.x;  // 32768 total
    const int e  = idx >> 7;
    const int kq = idx & 127;
    const int k  = kq * 4;
    const int kc = k >> 7;
    const int kl = k & 127;
    float4v wv = *(const float4v*)(weight + (size_t)e * KDIM + k);
    *(short4v*)(wimg + kc * 65536 + e * 256 +
                (((unsigned)(kl * 2)) ^ ((unsigned)(e & 7) << 4))) = pack4(wv);
  }
}

// ---------------------------------------------------------------------------
// Kernel 1: gather + mean from bf16 features -> X image. One wave per row;
// 17 asm loads all in flight, single vmcnt(0). NT stores: the 51MB X stream
// must not evict the feature table from L3.
// ---------------------------------------------------------------------------
__global__ __launch_bounds__(256, 4) void gather_mean_bf16(
    const int* __restrict__ nodes,
    const int* __restrict__ neigh,
    const unsigned short* __restrict__ fb,
    unsigned char* __restrict__ ximg) {
  const int l = threadIdx.x & 63;
  const int w = threadIdx.x >> 6;
  const int row = __builtin_amdgcn_readfirstlane(blockIdx.x * 4 + w);
  if (row >= B_PAD) return;

  const int blk  = row >> 6;
  const int rloc = row & 63;
  unsigned char* base = ximg + (size_t)blk * XBLK + rloc * 256;
  const unsigned int sw  = (unsigned)(rloc & 7) << 4;
  const unsigned int off = (((unsigned)(l * 8)) & 255u) ^ sw;
  const int kcs = l >> 5;

  if (row < B_TOTAL) {
    const size_t fo = (size_t)l * 4;   // 4 bf16 per lane per row
    const int node = nodes[row];
    uint2v vs  = ld8(fb + (size_t)node * FDIM + fo);
    uint2v n0  = ld8(fb + (size_t)neigh[row * NSAMP +  0] * FDIM + fo);
    uint2v n1  = ld8(fb + (size_t)neigh[row * NSAMP +  1] * FDIM + fo);
    uint2v n2  = ld8(fb + (size_t)neigh[row * NSAMP +  2] * FDIM + fo);
    uint2v n3  = ld8(fb + (size_t)neigh[row * NSAMP +  3] * FDIM + fo);
    uint2v n4  = ld8(fb + (size_t)neigh[row * NSAMP +  4] * FDIM + fo);
    uint2v n5  = ld8(fb + (size_t)neigh[row * NSAMP +  5] * FDIM + fo);
    uint2v n6  = ld8(fb + (size_t)neigh[row * NSAMP +  6] * FDIM + fo);
    uint2v n7  = ld8(fb + (size_t)neigh[row * NSAMP +  7] * FDIM + fo);
    uint2v n8  = ld8(fb + (size_t)neigh[row * NSAMP +  8] * FDIM + fo);
    uint2v n9  = ld8(fb + (size_t)neigh[row * NSAMP +  9] * FDIM + fo);
    uint2v n10 = ld8(fb + (size_t)neigh[row * NSAMP + 10] * FDIM + fo);
    uint2v n11 = ld8(fb + (size_t)neigh[row * NSAMP + 11] * FDIM + fo);
    uint2v n12 = ld8(fb + (size_t)neigh[row * NSAMP + 12] * FDIM + fo);
    uint2v n13 = ld8(fb + (size_t)neigh[row * NSAMP + 13] * FDIM + fo);
    uint2v n14 = ld8(fb + (size_t)neigh[row * NSAMP + 14] * FDIM + fo);
    uint2v n15 = ld8(fb + (size_t)neigh[row * NSAMP + 15] * FDIM + fo);
    asm volatile("s_waitcnt vmcnt(0)" ::: "memory");
    __builtin_amdgcn_sched_barrier(0);

    float4v a0  = bf4_to_f32(n0)  + bf4_to_f32(n1);
    float4v a1  = bf4_to_f32(n2)  + bf4_to_f32(n3);
    float4v a2  = bf4_to_f32(n4)  + bf4_to_f32(n5);
    float4v a3  = bf4_to_f32(n6)  + bf4_to_f32(n7);
    float4v a4  = bf4_to_f32(n8)  + bf4_to_f32(n9);
    float4v a5  = bf4_to_f32(n10) + bf4_to_f32(n11);
    float4v a6  = bf4_to_f32(n12) + bf4_to_f32(n13);
    float4v a7  = bf4_to_f32(n14) + bf4_to_f32(n15);
    a0 += a1; a2 += a3; a4 += a5; a6 += a7;
    a0 += a2; a4 += a6;
    a0 += a4;
    a0 *= 0.0625f;

    __builtin_nontemporal_store(vs,        (uint2v*)(base + kcs * XCHUNK + off));
    __builtin_nontemporal_store(pack4u(a0),(uint2v*)(base + (2 + kcs) * XCHUNK + off));
  } else {
    uint2v z = {0u, 0u};
    __builtin_nontemporal_store(z, (uint2v*)(base + kcs * XCHUNK + off));
    __builtin_nontemporal_store(z, (uint2v*)(base + (2 + kcs) * XCHUNK + off));
  }
}

// ---------------------------------------------------------------------------
// Kernel 2: out[e,b] = relu( sum_k W[e,k] * X[b,k] ), MFMA bf16. NT out
// stores (never re-read).
// ---------------------------------------------------------------------------
__global__ __launch_bounds__(256) void gemm_relu(
    const unsigned char* __restrict__ ximg,
    const unsigned char* __restrict__ wimg,
    float* __restrict__ out) {
  __shared__ alignas(16) unsigned char lds_w[EDIM * 256];   // 64KB
  __shared__ alignas(16) unsigned char lds_x[NBT * 256];    // 16KB

  const int tid = threadIdx.x;
  const int l   = tid & 63;
  const int w   = tid >> 6;
  const int lr  = l & 15;
  const int g   = l >> 4;
  const int b0  = blockIdx.x * NBT;
  const unsigned char* xsrc = ximg + (size_t)blockIdx.x * XBLK;

  float4v acc[4][4];
  #pragma unroll
  for (int mi = 0; mi < 4; ++mi)
    #pragma unroll
    for (int ni = 0; ni < 4; ++ni)
      acc[mi][ni] = (float4v){0.f, 0.f, 0.f, 0.f};

  for (int kc = 0; kc < 4; ++kc) {
    __syncthreads();
    {
      const unsigned char* ws_ = wimg + kc * 65536;
      #pragma unroll
      for (int i = 0; i < 16; ++i)
        lds_load16(ws_ + i * 4096 + tid * 16, lds_w + i * 4096 + (w << 10));
      const unsigned char* xs_ = xsrc + kc * XCHUNK;
      #pragma unroll
      for (int i = 0; i < 4; ++i)
        lds_load16(xs_ + i * 4096 + tid * 16, lds_x + i * 4096 + (w << 10));
    }
    __syncthreads();
    #pragma unroll
    for (int ks = 0; ks < 4; ++ks) {
      const int ko = ks * 32;
      short8v afr[4], bfr[4];
      #pragma unroll
      for (int mi = 0; mi < 4; ++mi) {
        const int e = w * 64 + mi * 16 + lr;
        const unsigned int sw = (unsigned)(e & 7) << 4;
        const unsigned char* base = lds_w + e * 256;
        short4v lo = *(const short4v*)(base + (((unsigned)((ko + 4 * g) * 2)) ^ sw));
        short4v hi = *(const short4v*)(base + (((unsigned)((ko + 16 + 4 * g) * 2)) ^ sw));
        afr[mi] = __builtin_shufflevector(lo, hi, 0, 1, 2, 3, 4, 5, 6, 7);
      }
      #pragma unroll
      for (int ni = 0; ni < 4; ++ni) {
        const int r = ni * 16 + lr;
        const unsigned int sw = (unsigned)(r & 7) << 4;
        const unsigned char* base = lds_x + r * 256;
        short4v lo = *(const short4v*)(base + (((unsigned)((ko + 4 * g) * 2)) ^ sw));
        short4v hi = *(const short4v*)(base + (((unsigned)((ko + 16 + 4 * g) * 2)) ^ sw));
        bfr[ni] = __builtin_shufflevector(lo, hi, 0, 1, 2, 3, 4, 5, 6, 7);
      }
      #pragma unroll
      for (int mi = 0; mi < 4; ++mi)
        #pragma unroll
        for (int ni = 0; ni < 4; ++ni)
          acc[mi][ni] = __builtin_amdgcn_mfma_f32_16x16x32_bf16(afr[mi], bfr[ni], acc[mi][ni], 0, 0, 0);
    }
  }

  #pragma unroll
  for (int ni = 0; ni < 4; ++ni) {
    const int b = b0 + ni * 16 + lr;
    if (b >= B_TOTAL) continue;
    #pragma unroll
    for (int mi = 0; mi < 4; ++mi) {
      const int e = w * 64 + mi * 16 + g * 4;
      #pragma unroll
      for (int q = 0; q < 4; ++q) {
        float v = acc[mi][ni][q];
        __builtin_nontemporal_store(v > 0.f ? v : 0.f,
                                    &out[(size_t)(e + q) * B_TOTAL + b]);
      }
    }
  }
}

// ---------------------------------------------------------------------------
// Fallback (ws too small): round-1 fused kernel, known-correct.
// ---------------------------------------------------------------------------
__global__ __launch_bounds__(256, 1) void encoder_fused(
    const int* __restrict__ nodes,
    const int* __restrict__ neigh,
    const float* __restrict__ features,
    const float* __restrict__ weight,
    float* __restrict__ out) {
  __shared__ alignas(16) unsigned char lds_cmb[64 * KDIM * 2];
  __shared__ alignas(16) unsigned char lds_w[EDIM * 128 * 2];

  const int tid = threadIdx.x;
  const int l   = tid & 63;
  const int w   = tid >> 6;
  const int b0  = blockIdx.x * 64;

  for (int rr = 0; rr < 16; ++rr) {
    const int r  = w * 16 + rr;
    const int rb = b0 + r;
    unsigned char* rowp = lds_cmb + r * (KDIM * 2);
    const unsigned int sw = (unsigned)(r & 7) << 4;
    if (rb < B_TOTAL) {
      const int node = nodes[rb];
      float4v selfv = *(const float4v*)(features + (size_t)node * FDIM + l * 4);
      float4v accv = {0.f, 0.f, 0.f, 0.f};
      #pragma unroll
      for (int s = 0; s < NSAMP; ++s) {
        const int ni = neigh[rb * NSAMP + s];
        accv += *(const float4v*)(features + (size_t)ni * FDIM + l * 4);
      }
      accv *= 0.0625f;
      *(short4v*)(rowp + (((unsigned)(l * 8)) ^ sw))       = pack4(selfv);
      *(short4v*)(rowp + (((unsigned)(512 + l * 8)) ^ sw)) = pack4(accv);
    } else {
      short4v z = {0, 0, 0, 0};
      *(short4v*)(rowp + (((unsigned)(l * 8)) ^ sw))       = z;
      *(short4v*)(rowp + (((unsigned)(512 + l * 8)) ^ sw)) = z;
    }
  }

  const int lr = l & 15;
  const int g  = l >> 4;
  float4v acc[4][4];
  #pragma unroll
  for (int mi = 0; mi < 4; ++mi)
    #pragma unroll
    for (int ni = 0; ni < 4; ++ni)
      acc[mi][ni] = (float4v){0.f, 0.f, 0.f, 0.f};

  for (int kc = 0; kc < 4; ++kc) {
    __syncthreads();
    const int k0 = kc * 128;
    for (int i = tid; i < EDIM * 32; i += 256) {
      const int e  = i >> 5;
      const int kq = i & 31;
      float4v wv = *(const float4v*)(weight + (size_t)e * KDIM + k0 + kq * 4);
      *(short4v*)(lds_w + e * 256 + (((unsigned)(kq * 8)) ^ ((unsigned)(e & 7) << 4))) = pack4(wv);
    }
    __syncthreads();
    #pragma unroll
    for (int ks = 0; ks < 4; ++ks) {
      const int ko = ks * 32;
      short8v afr[4], bfr[4];
      #pragma unroll
      for (int mi = 0; mi < 4; ++mi) {
        const int e = w * 64 + mi * 16 + lr;
        const unsigned int sw = (unsigned)(e & 7) << 4;
        const unsigned char* base = lds_w + e * 256;
        short4v lo = *(const short4v*)(base + (((unsigned)((ko + 4 * g) * 2)) ^ sw));
        short4v hi = *(const short4v*)(base + (((unsigned)((ko + 16 + 4 * g) * 2)) ^ sw));
        afr[mi] = __builtin_shufflevector(lo, hi, 0, 1, 2, 3, 4, 5, 6, 7);
      }
      #pragma unroll
      for (int ni = 0; ni < 4; ++ni) {
        const int rrow = ni * 16 + lr;
        const unsigned int sw = (unsigned)(rrow & 7) << 4;
        const unsigned char* base = lds_cmb + rrow * (KDIM * 2);
        const int kk = k0 + ko;
        short4v lo = *(const short4v*)(base + (((unsigned)((kk + 4 * g) * 2)) ^ sw));
        short4v hi = *(const short4v*)(base + (((unsigned)((kk + 16 + 4 * g) * 2)) ^ sw));
        bfr[ni] = __builtin_shufflevector(lo, hi, 0, 1, 2, 3, 4, 5, 6, 7);
      }
      #pragma unroll
      for (int mi = 0; mi < 4; ++mi)
        #pragma unroll
        for (int ni = 0; ni < 4; ++ni)
          acc[mi][ni] = __builtin_amdgcn_mfma_f32_16x16x32_bf16(afr[mi], bfr[ni], acc[mi][ni], 0, 0, 0);
    }
  }

  #pragma unroll
  for (int ni = 0; ni < 4; ++ni) {
    const int b = b0 + ni * 16 + lr;
    if (b >= B_TOTAL) continue;
    #pragma unroll
    for (int mi = 0; mi < 4; ++mi) {
      const int e = w * 64 + mi * 16 + g * 4;
      #pragma unroll
      for (int q = 0; q < 4; ++q) {
        float v = acc[mi][ni][q];
        out[(size_t)(e + q) * B_TOTAL + b] = v > 0.f ? v : 0.f;
      }
    }
  }
}

extern "C" void kernel_launch(void* const* d_in, const int* in_sizes, int n_in,
                              void* d_out, int out_size, void* d_ws, size_t ws_size,
                              hipStream_t stream) {
  const int*   nodes    = (const int*)d_in[0];
  const int*   neigh    = (const int*)d_in[1];
  const float* features = (const float*)d_in[2];
  const float* weight   = (const float*)d_in[3];
  float*       out      = (float*)d_out;

  if (ws_size >= FB_OFF + FB_SZ) {
    unsigned char*  ximg = (unsigned char*)d_ws;
    unsigned char*  wimg = (unsigned char*)d_ws + WIMG_OFF;
    unsigned short* fb   = (unsigned short*)((unsigned char*)d_ws + FB_OFF);
    prep_pack<<<FP_BLOCKS + PW_BLOCKS, 256, 0, stream>>>(features, fb, weight, wimg);
    gather_mean_bf16<<<B_PAD / 4, 256, 0, stream>>>(nodes, neigh, fb, ximg);
    gemm_relu<<<NBLK, 256, 0, stream>>>(ximg, wimg, out);
  } else {
    encoder_fused<<<(B_TOTAL + 63) / 64, 256, 0, stream>>>(nodes, neigh, features, weight, out);
  }
}

// Round 8
// 126.371 us; speedup vs baseline: 1.5953x; 1.0251x over previous
//
#include <hip/hip_runtime.h>

#define N_NODES 100000
#define B_TOTAL 50000
#define NSAMP   16
#define FDIM    256
#define KDIM    512   // 2*FDIM
#define EDIM    256
#define NBT     64    // batch columns per GEMM block
#define B_PAD   50048 // B_TOTAL rounded to NBT
#define NBLK    (B_PAD / NBT)   // 782

// X image: [blk][kc=4][rloc=64][256B swizzled]  -> 64KB per blk, 50.05MB total
#define XCHUNK  16384            // 64 rows * 256B
#define XBLK    (4 * XCHUNK)     // 65536
// W image: [kc=4][e=256][256B swizzled] -> 256KB, after X image in ws
#define WIMG_OFF ((size_t)NBLK * XBLK)
#define WIMG_SZ  (4 * 65536)
// bf16 feature image after W image
#define FB_OFF   (WIMG_OFF + WIMG_SZ)
#define FB_SZ    ((size_t)N_NODES * FDIM * 2)

#define GQ_BPP   (B_PAD / 16)    // gather blocks per pass = 3128

typedef __attribute__((ext_vector_type(4))) float float4v;
typedef __attribute__((ext_vector_type(4))) short short4v;
typedef __attribute__((ext_vector_type(8))) short short8v;
typedef __attribute__((ext_vector_type(2))) unsigned int uint2v;

__device__ __forceinline__ unsigned short f2bf(float f) {
  unsigned int u = __builtin_bit_cast(unsigned int, f);
  u += 0x7FFFu + ((u >> 16) & 1u);   // round-to-nearest-even
  return (unsigned short)(u >> 16);
}

__device__ __forceinline__ short4v pack4(float4v v) {
  short4v r;
  r[0] = (short)f2bf(v[0]);
  r[1] = (short)f2bf(v[1]);
  r[2] = (short)f2bf(v[2]);
  r[3] = (short)f2bf(v[3]);
  return r;
}

__device__ __forceinline__ uint2v pack4u(float4v v) {
  unsigned int lo = ((unsigned)f2bf(v[1]) << 16) | f2bf(v[0]);
  unsigned int hi = ((unsigned)f2bf(v[3]) << 16) | f2bf(v[2]);
  uint2v r; r[0] = lo; r[1] = hi;
  return r;
}

__device__ __forceinline__ float4v bf4_to_f32(uint2v u) {
  float4v r;
  r[0] = __builtin_bit_cast(float, u[0] << 16);
  r[1] = __builtin_bit_cast(float, u[0] & 0xffff0000u);
  r[2] = __builtin_bit_cast(float, u[1] << 16);
  r[3] = __builtin_bit_cast(float, u[1] & 0xffff0000u);
  return r;
}

// Inline-asm 8B load: compiler cannot serialize these; we wait manually.
__device__ __forceinline__ uint2v ld8(const void* p) {
  uint2v r;
  asm volatile("global_load_dwordx2 %0, %1, off" : "=v"(r) : "v"(p) : "memory");
  return r;
}

__device__ __forceinline__ void lds_load16(const void* g, void* l) {
  __builtin_amdgcn_global_load_lds(
      (const __attribute__((address_space(1))) unsigned int*)g,
      (__attribute__((address_space(3))) unsigned int*)l, 16, 0, 0);
}

// ---------------------------------------------------------------------------
// Kernel A: features f32 -> bf16 linear image (one-time, 102R + 51W MB).
// ---------------------------------------------------------------------------
__global__ __launch_bounds__(256) void feat_pack(
    const float* __restrict__ f, unsigned short* __restrict__ o) {
  const size_t i = ((size_t)blockIdx.x * 256 + threadIdx.x) * 8;
  if (i >= (size_t)N_NODES * FDIM) return;
  float4v a = *(const float4v*)(f + i);
  float4v b = *(const float4v*)(f + i + 4);
  short4v ra = pack4(a), rb = pack4(b);
  short8v r;
  r[0]=ra[0]; r[1]=ra[1]; r[2]=ra[2]; r[3]=ra[3];
  r[4]=rb[0]; r[5]=rb[1]; r[6]=rb[2]; r[7]=rb[3];
  *(short8v*)(o + i) = r;
}

// ---------------------------------------------------------------------------
// Kernel 0: pack W f32 [256][512] -> bf16 swizzled image in ws.
// ---------------------------------------------------------------------------
__global__ __launch_bounds__(256) void pack_w(
    const float* __restrict__ weight, unsigned char* __restrict__ wimg) {
  const int idx = blockIdx.x * 256 + threadIdx.x;   // 32768 total
  const int e  = idx >> 7;
  const int kq = idx & 127;
  const int k  = kq * 4;
  const int kc = k >> 7;
  const int kl = k & 127;
  float4v wv = *(const float4v*)(weight + (size_t)e * KDIM + k);
  *(short4v*)(wimg + kc * 65536 + e * 256 +
              (((unsigned)(kl * 2)) ^ ((unsigned)(e & 7) << 4))) = pack4(wv);
}

// ---------------------------------------------------------------------------
// Kernel 1: column-sliced gather. Pass p (= blockIdx.x / GQ_BPP, dispatched
// pass-major so passes are ~temporally separated) covers feature cols
// [p*64, p*64+64) -> 128B per row reference. Working set per pass = 12.8MB
// -> per-XCD L2 holds 32k quarter-rows vs ~12.5k-ref reuse gap -> high hit.
// 16 lanes per row, 4 rows per wave, 16 rows per block; 17 asm loads in
// flight per lane, single vmcnt(0).
// ---------------------------------------------------------------------------
__global__ __launch_bounds__(256, 4) void gather_quarter(
    const int* __restrict__ nodes,
    const int* __restrict__ neigh,
    const unsigned short* __restrict__ fb,
    unsigned char* __restrict__ ximg) {
  const int tid  = threadIdx.x;
  const int l    = tid & 63;
  const int w    = tid >> 6;
  const int li   = l & 15;       // lane within row (covers 8B of the 128B slice)
  const int rl   = l >> 4;       // row within wave
  const int pass = blockIdx.x / GQ_BPP;
  const int bi   = blockIdx.x - pass * GQ_BPP;
  const int row  = bi * 16 + w * 4 + rl;

  const size_t fo = (size_t)pass * 64 + li * 4;   // bf16 element offset in row

  // X-image addressing (matches gemm_relu's reader exactly)
  const int blk  = row >> 6;
  const int rloc = row & 63;
  unsigned char* base = ximg + (size_t)blk * XBLK + rloc * 256;
  const unsigned int bo = (unsigned)(((pass & 1) << 7) + li * 8);
  const unsigned int sw = (unsigned)(rloc & 7) << 4;
  const unsigned int off = bo ^ sw;
  const int cs = pass >> 1;       // self chunk 0/1 ; mean chunk 2/3

  if (row < B_TOTAL) {
    const int node = nodes[row];
    const int* ni = neigh + row * NSAMP;
    uint2v vs  = ld8(fb + (size_t)node  * FDIM + fo);
    uint2v n0  = ld8(fb + (size_t)ni[ 0] * FDIM + fo);
    uint2v n1  = ld8(fb + (size_t)ni[ 1] * FDIM + fo);
    uint2v n2  = ld8(fb + (size_t)ni[ 2] * FDIM + fo);
    uint2v n3  = ld8(fb + (size_t)ni[ 3] * FDIM + fo);
    uint2v n4  = ld8(fb + (size_t)ni[ 4] * FDIM + fo);
    uint2v n5  = ld8(fb + (size_t)ni[ 5] * FDIM + fo);
    uint2v n6  = ld8(fb + (size_t)ni[ 6] * FDIM + fo);
    uint2v n7  = ld8(fb + (size_t)ni[ 7] * FDIM + fo);
    uint2v n8  = ld8(fb + (size_t)ni[ 8] * FDIM + fo);
    uint2v n9  = ld8(fb + (size_t)ni[ 9] * FDIM + fo);
    uint2v n10 = ld8(fb + (size_t)ni[10] * FDIM + fo);
    uint2v n11 = ld8(fb + (size_t)ni[11] * FDIM + fo);
    uint2v n12 = ld8(fb + (size_t)ni[12] * FDIM + fo);
    uint2v n13 = ld8(fb + (size_t)ni[13] * FDIM + fo);
    uint2v n14 = ld8(fb + (size_t)ni[14] * FDIM + fo);
    uint2v n15 = ld8(fb + (size_t)ni[15] * FDIM + fo);
    asm volatile("s_waitcnt vmcnt(0)" ::: "memory");
    __builtin_amdgcn_sched_barrier(0);

    float4v a0  = bf4_to_f32(n0)  + bf4_to_f32(n1);
    float4v a1  = bf4_to_f32(n2)  + bf4_to_f32(n3);
    float4v a2  = bf4_to_f32(n4)  + bf4_to_f32(n5);
    float4v a3  = bf4_to_f32(n6)  + bf4_to_f32(n7);
    float4v a4  = bf4_to_f32(n8)  + bf4_to_f32(n9);
    float4v a5  = bf4_to_f32(n10) + bf4_to_f32(n11);
    float4v a6  = bf4_to_f32(n12) + bf4_to_f32(n13);
    float4v a7  = bf4_to_f32(n14) + bf4_to_f32(n15);
    a0 += a1; a2 += a3; a4 += a5; a6 += a7;
    a0 += a2; a4 += a6;
    a0 += a4;
    a0 *= 0.0625f;

    *(uint2v*)(base + cs * XCHUNK + off)       = vs;
    *(uint2v*)(base + (2 + cs) * XCHUNK + off) = pack4u(a0);
  } else if (row < B_PAD) {
    uint2v z = {0u, 0u};
    *(uint2v*)(base + cs * XCHUNK + off)       = z;
    *(uint2v*)(base + (2 + cs) * XCHUNK + off) = z;
  }
}

// ---------------------------------------------------------------------------
// Kernel 2: out[e,b] = relu( sum_k W[e,k] * X[b,k] ), MFMA bf16.
// ---------------------------------------------------------------------------
__global__ __launch_bounds__(256) void gemm_relu(
    const unsigned char* __restrict__ ximg,
    const unsigned char* __restrict__ wimg,
    float* __restrict__ out) {
  __shared__ alignas(16) unsigned char lds_w[EDIM * 256];   // 64KB
  __shared__ alignas(16) unsigned char lds_x[NBT * 256];    // 16KB

  const int tid = threadIdx.x;
  const int l   = tid & 63;
  const int w   = tid >> 6;
  const int lr  = l & 15;
  const int g   = l >> 4;
  const int b0  = blockIdx.x * NBT;
  const unsigned char* xsrc = ximg + (size_t)blockIdx.x * XBLK;

  float4v acc[4][4];
  #pragma unroll
  for (int mi = 0; mi < 4; ++mi)
    #pragma unroll
    for (int ni = 0; ni < 4; ++ni)
      acc[mi][ni] = (float4v){0.f, 0.f, 0.f, 0.f};

  for (int kc = 0; kc < 4; ++kc) {
    __syncthreads();
    {
      const unsigned char* ws_ = wimg + kc * 65536;
      #pragma unroll
      for (int i = 0; i < 16; ++i)
        lds_load16(ws_ + i * 4096 + tid * 16, lds_w + i * 4096 + (w << 10));
      const unsigned char* xs_ = xsrc + kc * XCHUNK;
      #pragma unroll
      for (int i = 0; i < 4; ++i)
        lds_load16(xs_ + i * 4096 + tid * 16, lds_x + i * 4096 + (w << 10));
    }
    __syncthreads();
    #pragma unroll
    for (int ks = 0; ks < 4; ++ks) {
      const int ko = ks * 32;
      short8v afr[4], bfr[4];
      #pragma unroll
      for (int mi = 0; mi < 4; ++mi) {
        const int e = w * 64 + mi * 16 + lr;
        const unsigned int sw = (unsigned)(e & 7) << 4;
        const unsigned char* base = lds_w + e * 256;
        short4v lo = *(const short4v*)(base + (((unsigned)((ko + 4 * g) * 2)) ^ sw));
        short4v hi = *(const short4v*)(base + (((unsigned)((ko + 16 + 4 * g) * 2)) ^ sw));
        afr[mi] = __builtin_shufflevector(lo, hi, 0, 1, 2, 3, 4, 5, 6, 7);
      }
      #pragma unroll
      for (int ni = 0; ni < 4; ++ni) {
        const int r = ni * 16 + lr;
        const unsigned int sw = (unsigned)(r & 7) << 4;
        const unsigned char* base = lds_x + r * 256;
        short4v lo = *(const short4v*)(base + (((unsigned)((ko + 4 * g) * 2)) ^ sw));
        short4v hi = *(const short4v*)(base + (((unsigned)((ko + 16 + 4 * g) * 2)) ^ sw));
        bfr[ni] = __builtin_shufflevector(lo, hi, 0, 1, 2, 3, 4, 5, 6, 7);
      }
      #pragma unroll
      for (int mi = 0; mi < 4; ++mi)
        #pragma unroll
        for (int ni = 0; ni < 4; ++ni)
          acc[mi][ni] = __builtin_amdgcn_mfma_f32_16x16x32_bf16(afr[mi], bfr[ni], acc[mi][ni], 0, 0, 0);
    }
  }

  #pragma unroll
  for (int ni = 0; ni < 4; ++ni) {
    const int b = b0 + ni * 16 + lr;
    if (b >= B_TOTAL) continue;
    #pragma unroll
    for (int mi = 0; mi < 4; ++mi) {
      const int e = w * 64 + mi * 16 + g * 4;
      #pragma unroll
      for (int q = 0; q < 4; ++q) {
        float v = acc[mi][ni][q];
        out[(size_t)(e + q) * B_TOTAL + b] = v > 0.f ? v : 0.f;
      }
    }
  }
}

// ---------------------------------------------------------------------------
// Fallback (ws too small): round-1 fused kernel, known-correct.
// ---------------------------------------------------------------------------
__global__ __launch_bounds__(256, 1) void encoder_fused(
    const int* __restrict__ nodes,
    const int* __restrict__ neigh,
    const float* __restrict__ features,
    const float* __restrict__ weight,
    float* __restrict__ out) {
  __shared__ alignas(16) unsigned char lds_cmb[64 * KDIM * 2];
  __shared__ alignas(16) unsigned char lds_w[EDIM * 128 * 2];

  const int tid = threadIdx.x;
  const int l   = tid & 63;
  const int w   = tid >> 6;
  const int b0  = blockIdx.x * 64;

  for (int rr = 0; rr < 16; ++rr) {
    const int r  = w * 16 + rr;
    const int rb = b0 + r;
    unsigned char* rowp = lds_cmb + r * (KDIM * 2);
    const unsigned int sw = (unsigned)(r & 7) << 4;
    if (rb < B_TOTAL) {
      const int node = nodes[rb];
      float4v selfv = *(const float4v*)(features + (size_t)node * FDIM + l * 4);
      float4v accv = {0.f, 0.f, 0.f, 0.f};
      #pragma unroll
      for (int s = 0; s < NSAMP; ++s) {
        const int ni = neigh[rb * NSAMP + s];
        accv += *(const float4v*)(features + (size_t)ni * FDIM + l * 4);
      }
      accv *= 0.0625f;
      *(short4v*)(rowp + (((unsigned)(l * 8)) ^ sw))       = pack4(selfv);
      *(short4v*)(rowp + (((unsigned)(512 + l * 8)) ^ sw)) = pack4(accv);
    } else {
      short4v z = {0, 0, 0, 0};
      *(short4v*)(rowp + (((unsigned)(l * 8)) ^ sw))       = z;
      *(short4v*)(rowp + (((unsigned)(512 + l * 8)) ^ sw)) = z;
    }
  }

  const int lr = l & 15;
  const int g  = l >> 4;
  float4v acc[4][4];
  #pragma unroll
  for (int mi = 0; mi < 4; ++mi)
    #pragma unroll
    for (int ni = 0; ni < 4; ++ni)
      acc[mi][ni] = (float4v){0.f, 0.f, 0.f, 0.f};

  for (int kc = 0; kc < 4; ++kc) {
    __syncthreads();
    const int k0 = kc * 128;
    for (int i = tid; i < EDIM * 32; i += 256) {
      const int e  = i >> 5;
      const int kq = i & 31;
      float4v wv = *(const float4v*)(weight + (size_t)e * KDIM + k0 + kq * 4);
      *(short4v*)(lds_w + e * 256 + (((unsigned)(kq * 8)) ^ ((unsigned)(e & 7) << 4))) = pack4(wv);
    }
    __syncthreads();
    #pragma unroll
    for (int ks = 0; ks < 4; ++ks) {
      const int ko = ks * 32;
      short8v afr[4], bfr[4];
      #pragma unroll
      for (int mi = 0; mi < 4; ++mi) {
        const int e = w * 64 + mi * 16 + lr;
        const unsigned int sw = (unsigned)(e & 7) << 4;
        const unsigned char* base = lds_w + e * 256;
        short4v lo = *(const short4v*)(base + (((unsigned)((ko + 4 * g) * 2)) ^ sw));
        short4v hi = *(const short4v*)(base + (((unsigned)((ko + 16 + 4 * g) * 2)) ^ sw));
        afr[mi] = __builtin_shufflevector(lo, hi, 0, 1, 2, 3, 4, 5, 6, 7);
      }
      #pragma unroll
      for (int ni = 0; ni < 4; ++ni) {
        const int rrow = ni * 16 + lr;
        const unsigned int sw = (unsigned)(rrow & 7) << 4;
        const unsigned char* base = lds_cmb + rrow * (KDIM * 2);
        const int kk = k0 + ko;
        short4v lo = *(const short4v*)(base + (((unsigned)((kk + 4 * g) * 2)) ^ sw));
        short4v hi = *(const short4v*)(base + (((unsigned)((kk + 16 + 4 * g) * 2)) ^ sw));
        bfr[ni] = __builtin_shufflevector(lo, hi, 0, 1, 2, 3, 4, 5, 6, 7);
      }
      #pragma unroll
      for (int mi = 0; mi < 4; ++mi)
        #pragma unroll
        for (int ni = 0; ni < 4; ++ni)
          acc[mi][ni] = __builtin_amdgcn_mfma_f32_16x16x32_bf16(afr[mi], bfr[ni], acc[mi][ni], 0, 0, 0);
    }
  }

  #pragma unroll
  for (int ni = 0; ni < 4; ++ni) {
    const int b = b0 + ni * 16 + lr;
    if (b >= B_TOTAL) continue;
    #pragma unroll
    for (int mi = 0; mi < 4; ++mi) {
      const int e = w * 64 + mi * 16 + g * 4;
      #pragma unroll
      for (int q = 0; q < 4; ++q) {
        float v = acc[mi][ni][q];
        out[(size_t)(e + q) * B_TOTAL + b] = v > 0.f ? v : 0.f;
      }
    }
  }
}

extern "C" void kernel_launch(void* const* d_in, const int* in_sizes, int n_in,
                              void* d_out, int out_size, void* d_ws, size_t ws_size,
                              hipStream_t stream) {
  const int*   nodes    = (const int*)d_in[0];
  const int*   neigh    = (const int*)d_in[1];
  const float* features = (const float*)d_in[2];
  const float* weight   = (const float*)d_in[3];
  float*       out      = (float*)d_out;

  if (ws_size >= FB_OFF + FB_SZ) {
    unsigned char*  ximg = (unsigned char*)d_ws;
    unsigned char*  wimg = (unsigned char*)d_ws + WIMG_OFF;
    unsigned short* fb   = (unsigned short*)((unsigned char*)d_ws + FB_OFF);
    feat_pack<<<(N_NODES * FDIM / 8 + 255) / 256, 256, 0, stream>>>(features, fb);
    pack_w<<<128, 256, 0, stream>>>(weight, wimg);
    gather_quarter<<<4 * GQ_BPP, 256, 0, stream>>>(nodes, neigh, fb, ximg);
    gemm_relu<<<NBLK, 256, 0, stream>>>(ximg, wimg, out);
  } else {
    encoder_fused<<<(B_TOTAL + 63) / 64, 256, 0, stream>>>(nodes, neigh, features, weight, out);
  }
}

// Round 9
// 93.084 us; speedup vs baseline: 2.1658x; 1.3576x over previous
//
#include <hip/hip_runtime.h>

#define N_NODES 100000
#define B_TOTAL 50000
#define NSAMP   16
#define FDIM    256
#define KDIM    512   // 2*FDIM
#define EDIM    256
#define NBT     64    // batch columns per GEMM block
#define B_PAD   50048 // B_TOTAL rounded to NBT
#define NBLK    (B_PAD / NBT)   // 782

// X image: [blk][kc=4][rloc=64][256B swizzled]  -> 64KB per blk, 50.05MB total
#define XCHUNK  16384            // 64 rows * 256B
#define XBLK    (4 * XCHUNK)     // 65536
// W image: [kc=4][e=256][256B swizzled] -> 256KB, after X image in ws
#define WIMG_OFF ((size_t)NBLK * XBLK)
#define WIMG_SZ  (4 * 65536)
// fp8 feature table after W image: [N_NODES][256] e4m3 = 25.6MB
#define F8_OFF   (WIMG_OFF + WIMG_SZ)
#define F8_SZ    ((size_t)N_NODES * FDIM)

typedef __attribute__((ext_vector_type(4))) float float4v;
typedef __attribute__((ext_vector_type(2))) float float2v;
typedef __attribute__((ext_vector_type(4))) short short4v;
typedef __attribute__((ext_vector_type(8))) short short8v;
typedef __attribute__((ext_vector_type(2))) unsigned int uint2v;

__device__ __forceinline__ unsigned short f2bf(float f) {
  unsigned int u = __builtin_bit_cast(unsigned int, f);
  u += 0x7FFFu + ((u >> 16) & 1u);   // round-to-nearest-even
  return (unsigned short)(u >> 16);
}

__device__ __forceinline__ short4v pack4(float4v v) {
  short4v r;
  r[0] = (short)f2bf(v[0]);
  r[1] = (short)f2bf(v[1]);
  r[2] = (short)f2bf(v[2]);
  r[3] = (short)f2bf(v[3]);
  return r;
}

// ---------------- fp8 e4m3fn encode/decode (hw builtin if available) -------
#if defined(__has_builtin)
#if __has_builtin(__builtin_amdgcn_cvt_pk_f32_fp8) && __has_builtin(__builtin_amdgcn_cvt_pk_fp8_f32)
#define HAS_HW_FP8 1
#endif
#endif

#ifdef HAS_HW_FP8
__device__ __forceinline__ float2v f8_lo(unsigned int d) {
  return (float2v)__builtin_amdgcn_cvt_pk_f32_fp8((int)d, false);
}
__device__ __forceinline__ float2v f8_hi(unsigned int d) {
  return (float2v)__builtin_amdgcn_cvt_pk_f32_fp8((int)d, true);
}
__device__ __forceinline__ uint2v f8_enc8(float4v a, float4v b) {
  int w0 = __builtin_amdgcn_cvt_pk_fp8_f32(a[0], a[1], 0, false);
  w0 = __builtin_amdgcn_cvt_pk_fp8_f32(a[2], a[3], w0, true);
  int w1 = __builtin_amdgcn_cvt_pk_fp8_f32(b[0], b[1], 0, false);
  w1 = __builtin_amdgcn_cvt_pk_fp8_f32(b[2], b[3], w1, true);
  uint2v r; r[0] = (unsigned)w0; r[1] = (unsigned)w1;
  return r;
}
#else
__device__ __forceinline__ float f8_dec1(unsigned int b) {
  unsigned int s = b >> 7, e = (b >> 3) & 15, m = b & 7;
  float fn = __builtin_bit_cast(float, (s << 31) | ((e + 120) << 23) | (m << 20));
  float fs = (float)(int)m * 0.001953125f;       // m * 2^-9
  fs = s ? -fs : fs;
  return e ? fn : fs;
}
__device__ __forceinline__ float2v f8_lo(unsigned int d) {
  float2v r; r[0] = f8_dec1(d & 255u); r[1] = f8_dec1((d >> 8) & 255u); return r;
}
__device__ __forceinline__ float2v f8_hi(unsigned int d) {
  float2v r; r[0] = f8_dec1((d >> 16) & 255u); r[1] = f8_dec1(d >> 24); return r;
}
__device__ __forceinline__ unsigned int f8_enc1(float x) {
  unsigned int u = __builtin_bit_cast(unsigned int, x);
  unsigned int s = (u >> 31) << 7;
  float ax = __builtin_fabsf(x);
  if (ax < 0.015625f) {                          // subnormal: m = RNE(ax*512)
    unsigned int m = (unsigned int)__builtin_rintf(ax * 512.0f);
    return s | m;                                // m==8 lands on min-normal bits
  }
  if (ax > 448.0f) return s | 0x7E;
  unsigned int au = u & 0x7fffffffu;
  unsigned int t = au + 0x7FFFFu + ((au >> 20) & 1u);   // RNE into 3-bit mantissa
  unsigned int E = t >> 23;
  return s | (((E - 120u) & 0xFu) << 3) | ((t >> 20) & 7u);
}
__device__ __forceinline__ uint2v f8_enc8(float4v a, float4v b) {
  uint2v r;
  r[0] = f8_enc1(a[0]) | (f8_enc1(a[1]) << 8) | (f8_enc1(a[2]) << 16) | (f8_enc1(a[3]) << 24);
  r[1] = f8_enc1(b[0]) | (f8_enc1(b[1]) << 8) | (f8_enc1(b[2]) << 16) | (f8_enc1(b[3]) << 24);
  return r;
}
#endif

// Inline-asm loads: compiler cannot serialize these; we wait manually.
__device__ __forceinline__ unsigned int ld4(const void* p) {
  unsigned int r;
  asm volatile("global_load_dword %0, %1, off" : "=v"(r) : "v"(p) : "memory");
  return r;
}
__device__ __forceinline__ float4v ld16f(const void* p) {
  float4v r;
  asm volatile("global_load_dwordx4 %0, %1, off" : "=v"(r) : "v"(p) : "memory");
  return r;
}

__device__ __forceinline__ void lds_load16(const void* g, void* l) {
  __builtin_amdgcn_global_load_lds(
      (const __attribute__((address_space(1))) unsigned int*)g,
      (__attribute__((address_space(3))) unsigned int*)l, 16, 0, 0);
}

// ---------------------------------------------------------------------------
// Kernel A: features f32 -> fp8 e4m3 table (one-time, 102R + 26W MB).
// ---------------------------------------------------------------------------
__global__ __launch_bounds__(256) void fp8_pack(
    const float* __restrict__ f, unsigned char* __restrict__ o) {
  const size_t i = ((size_t)blockIdx.x * 256 + threadIdx.x) * 8;
  if (i >= (size_t)N_NODES * FDIM) return;
  float4v a = *(const float4v*)(f + i);
  float4v b = *(const float4v*)(f + i + 4);
  *(uint2v*)(o + i) = f8_enc8(a, b);
}

// ---------------------------------------------------------------------------
// Kernel 0: pack W f32 [256][512] -> bf16 swizzled image in ws.
// ---------------------------------------------------------------------------
__global__ __launch_bounds__(256) void pack_w(
    const float* __restrict__ weight, unsigned char* __restrict__ wimg) {
  const int idx = blockIdx.x * 256 + threadIdx.x;   // 32768 total
  const int e  = idx >> 7;
  const int kq = idx & 127;
  const int k  = kq * 4;
  const int kc = k >> 7;
  const int kl = k & 127;
  float4v wv = *(const float4v*)(weight + (size_t)e * KDIM + k);
  *(short4v*)(wimg + kc * 65536 + e * 256 +
              (((unsigned)(kl * 2)) ^ ((unsigned)(e & 7) << 4))) = pack4(wv);
}

// ---------------------------------------------------------------------------
// Kernel 1: gather + mean. Self read f32 (full precision, un-averaged);
// neighbors read fp8 (error damped 4x by the 1/16 mean). One wave per row,
// 17 asm loads in flight, single vmcnt(0). Demand: 256MB vs bf16's 435MB.
// ---------------------------------------------------------------------------
__global__ __launch_bounds__(256, 4) void gather_mean_f8(
    const int* __restrict__ nodes,
    const int* __restrict__ neigh,
    const float* __restrict__ features,
    const unsigned char* __restrict__ f8,
    unsigned char* __restrict__ ximg) {
  const int l = threadIdx.x & 63;
  const int w = threadIdx.x >> 6;
  const int row = __builtin_amdgcn_readfirstlane(blockIdx.x * 4 + w);
  if (row >= B_PAD) return;

  const int blk  = row >> 6;
  const int rloc = row & 63;
  unsigned char* base = ximg + (size_t)blk * XBLK + rloc * 256;
  const unsigned int sw  = (unsigned)(rloc & 7) << 4;
  const unsigned int off = (((unsigned)(l * 8)) & 255u) ^ sw;
  const int kcs = l >> 5;

  if (row < B_TOTAL) {
    const int node = nodes[row];
    const int* ni = neigh + row * NSAMP;
    float4v vs = ld16f(features + (size_t)node * FDIM + l * 4);   // 16B f32 self
    const size_t fo = (size_t)l * 4;                              // 4B fp8 per lane
    unsigned int d0  = ld4(f8 + (size_t)ni[ 0] * FDIM + fo);
    unsigned int d1  = ld4(f8 + (size_t)ni[ 1] * FDIM + fo);
    unsigned int d2  = ld4(f8 + (size_t)ni[ 2] * FDIM + fo);
    unsigned int d3  = ld4(f8 + (size_t)ni[ 3] * FDIM + fo);
    unsigned int d4  = ld4(f8 + (size_t)ni[ 4] * FDIM + fo);
    unsigned int d5  = ld4(f8 + (size_t)ni[ 5] * FDIM + fo);
    unsigned int d6  = ld4(f8 + (size_t)ni[ 6] * FDIM + fo);
    unsigned int d7  = ld4(f8 + (size_t)ni[ 7] * FDIM + fo);
    unsigned int d8  = ld4(f8 + (size_t)ni[ 8] * FDIM + fo);
    unsigned int d9  = ld4(f8 + (size_t)ni[ 9] * FDIM + fo);
    unsigned int d10 = ld4(f8 + (size_t)ni[10] * FDIM + fo);
    unsigned int d11 = ld4(f8 + (size_t)ni[11] * FDIM + fo);
    unsigned int d12 = ld4(f8 + (size_t)ni[12] * FDIM + fo);
    unsigned int d13 = ld4(f8 + (size_t)ni[13] * FDIM + fo);
    unsigned int d14 = ld4(f8 + (size_t)ni[14] * FDIM + fo);
    unsigned int d15 = ld4(f8 + (size_t)ni[15] * FDIM + fo);
    asm volatile("s_waitcnt vmcnt(0)" ::: "memory");
    __builtin_amdgcn_sched_barrier(0);

    float2v lo0 = f8_lo(d0)  + f8_lo(d1);
    float2v lo1 = f8_lo(d2)  + f8_lo(d3);
    float2v lo2 = f8_lo(d4)  + f8_lo(d5);
    float2v lo3 = f8_lo(d6)  + f8_lo(d7);
    float2v lo4 = f8_lo(d8)  + f8_lo(d9);
    float2v lo5 = f8_lo(d10) + f8_lo(d11);
    float2v lo6 = f8_lo(d12) + f8_lo(d13);
    float2v lo7 = f8_lo(d14) + f8_lo(d15);
    lo0 += lo1; lo2 += lo3; lo4 += lo5; lo6 += lo7;
    lo0 += lo2; lo4 += lo6;
    lo0 += lo4;
    float2v hi0 = f8_hi(d0)  + f8_hi(d1);
    float2v hi1 = f8_hi(d2)  + f8_hi(d3);
    float2v hi2 = f8_hi(d4)  + f8_hi(d5);
    float2v hi3 = f8_hi(d6)  + f8_hi(d7);
    float2v hi4 = f8_hi(d8)  + f8_hi(d9);
    float2v hi5 = f8_hi(d10) + f8_hi(d11);
    float2v hi6 = f8_hi(d12) + f8_hi(d13);
    float2v hi7 = f8_hi(d14) + f8_hi(d15);
    hi0 += hi1; hi2 += hi3; hi4 += hi5; hi6 += hi7;
    hi0 += hi2; hi4 += hi6;
    hi0 += hi4;

    float4v a0;
    a0[0] = lo0[0] * 0.0625f;
    a0[1] = lo0[1] * 0.0625f;
    a0[2] = hi0[0] * 0.0625f;
    a0[3] = hi0[1] * 0.0625f;

    *(short4v*)(base + kcs * XCHUNK + off)       = pack4(vs);
    *(short4v*)(base + (2 + kcs) * XCHUNK + off) = pack4(a0);
  } else {
    short4v z = {0, 0, 0, 0};
    *(short4v*)(base + kcs * XCHUNK + off)       = z;
    *(short4v*)(base + (2 + kcs) * XCHUNK + off) = z;
  }
}

// ---------------------------------------------------------------------------
// Kernel 2: out[e,b] = relu( sum_k W[e,k] * X[b,k] ), MFMA bf16.
// ---------------------------------------------------------------------------
__global__ __launch_bounds__(256) void gemm_relu(
    const unsigned char* __restrict__ ximg,
    const unsigned char* __restrict__ wimg,
    float* __restrict__ out) {
  __shared__ alignas(16) unsigned char lds_w[EDIM * 256];   // 64KB
  __shared__ alignas(16) unsigned char lds_x[NBT * 256];    // 16KB

  const int tid = threadIdx.x;
  const int l   = tid & 63;
  const int w   = tid >> 6;
  const int lr  = l & 15;
  const int g   = l >> 4;
  const int b0  = blockIdx.x * NBT;
  const unsigned char* xsrc = ximg + (size_t)blockIdx.x * XBLK;

  float4v acc[4][4];
  #pragma unroll
  for (int mi = 0; mi < 4; ++mi)
    #pragma unroll
    for (int ni = 0; ni < 4; ++ni)
      acc[mi][ni] = (float4v){0.f, 0.f, 0.f, 0.f};

  typedef __attribute__((ext_vector_type(8))) short short8vv;
  for (int kc = 0; kc < 4; ++kc) {
    __syncthreads();
    {
      const unsigned char* ws_ = wimg + kc * 65536;
      #pragma unroll
      for (int i = 0; i < 16; ++i)
        lds_load16(ws_ + i * 4096 + tid * 16, lds_w + i * 4096 + (w << 10));
      const unsigned char* xs_ = xsrc + kc * XCHUNK;
      #pragma unroll
      for (int i = 0; i < 4; ++i)
        lds_load16(xs_ + i * 4096 + tid * 16, lds_x + i * 4096 + (w << 10));
    }
    __syncthreads();
    #pragma unroll
    for (int ks = 0; ks < 4; ++ks) {
      const int ko = ks * 32;
      short8vv afr[4], bfr[4];
      #pragma unroll
      for (int mi = 0; mi < 4; ++mi) {
        const int e = w * 64 + mi * 16 + lr;
        const unsigned int sw = (unsigned)(e & 7) << 4;
        const unsigned char* base = lds_w + e * 256;
        short4v lo = *(const short4v*)(base + (((unsigned)((ko + 4 * g) * 2)) ^ sw));
        short4v hi = *(const short4v*)(base + (((unsigned)((ko + 16 + 4 * g) * 2)) ^ sw));
        afr[mi] = __builtin_shufflevector(lo, hi, 0, 1, 2, 3, 4, 5, 6, 7);
      }
      #pragma unroll
      for (int ni = 0; ni < 4; ++ni) {
        const int r = ni * 16 + lr;
        const unsigned int sw = (unsigned)(r & 7) << 4;
        const unsigned char* base = lds_x + r * 256;
        short4v lo = *(const short4v*)(base + (((unsigned)((ko + 4 * g) * 2)) ^ sw));
        short4v hi = *(const short4v*)(base + (((unsigned)((ko + 16 + 4 * g) * 2)) ^ sw));
        bfr[ni] = __builtin_shufflevector(lo, hi, 0, 1, 2, 3, 4, 5, 6, 7);
      }
      #pragma unroll
      for (int mi = 0; mi < 4; ++mi)
        #pragma unroll
        for (int ni = 0; ni < 4; ++ni)
          acc[mi][ni] = __builtin_amdgcn_mfma_f32_16x16x32_bf16(afr[mi], bfr[ni], acc[mi][ni], 0, 0, 0);
    }
  }

  #pragma unroll
  for (int ni = 0; ni < 4; ++ni) {
    const int b = b0 + ni * 16 + lr;
    if (b >= B_TOTAL) continue;
    #pragma unroll
    for (int mi = 0; mi < 4; ++mi) {
      const int e = w * 64 + mi * 16 + g * 4;
      #pragma unroll
      for (int q = 0; q < 4; ++q) {
        float v = acc[mi][ni][q];
        out[(size_t)(e + q) * B_TOTAL + b] = v > 0.f ? v : 0.f;
      }
    }
  }
}

// ---------------------------------------------------------------------------
// Fallback (ws too small): round-1 fused kernel, known-correct.
// ---------------------------------------------------------------------------
__global__ __launch_bounds__(256, 1) void encoder_fused(
    const int* __restrict__ nodes,
    const int* __restrict__ neigh,
    const float* __restrict__ features,
    const float* __restrict__ weight,
    float* __restrict__ out) {
  __shared__ alignas(16) unsigned char lds_cmb[64 * KDIM * 2];
  __shared__ alignas(16) unsigned char lds_w[EDIM * 128 * 2];

  const int tid = threadIdx.x;
  const int l   = tid & 63;
  const int w   = tid >> 6;
  const int b0  = blockIdx.x * 64;

  for (int rr = 0; rr < 16; ++rr) {
    const int r  = w * 16 + rr;
    const int rb = b0 + r;
    unsigned char* rowp = lds_cmb + r * (KDIM * 2);
    const unsigned int sw = (unsigned)(r & 7) << 4;
    if (rb < B_TOTAL) {
      const int node = nodes[rb];
      float4v selfv = *(const float4v*)(features + (size_t)node * FDIM + l * 4);
      float4v accv = {0.f, 0.f, 0.f, 0.f};
      #pragma unroll
      for (int s = 0; s < NSAMP; ++s) {
        const int ni = neigh[rb * NSAMP + s];
        accv += *(const float4v*)(features + (size_t)ni * FDIM + l * 4);
      }
      accv *= 0.0625f;
      *(short4v*)(rowp + (((unsigned)(l * 8)) ^ sw))       = pack4(selfv);
      *(short4v*)(rowp + (((unsigned)(512 + l * 8)) ^ sw)) = pack4(accv);
    } else {
      short4v z = {0, 0, 0, 0};
      *(short4v*)(rowp + (((unsigned)(l * 8)) ^ sw))       = z;
      *(short4v*)(rowp + (((unsigned)(512 + l * 8)) ^ sw)) = z;
    }
  }

  const int lr = l & 15;
  const int g  = l >> 4;
  float4v acc[4][4];
  #pragma unroll
  for (int mi = 0; mi < 4; ++mi)
    #pragma unroll
    for (int ni = 0; ni < 4; ++ni)
      acc[mi][ni] = (float4v){0.f, 0.f, 0.f, 0.f};

  for (int kc = 0; kc < 4; ++kc) {
    __syncthreads();
    const int k0 = kc * 128;
    for (int i = tid; i < EDIM * 32; i += 256) {
      const int e  = i >> 5;
      const int kq = i & 31;
      float4v wv = *(const float4v*)(weight + (size_t)e * KDIM + k0 + kq * 4);
      *(short4v*)(lds_w + e * 256 + (((unsigned)(kq * 8)) ^ ((unsigned)(e & 7) << 4))) = pack4(wv);
    }
    __syncthreads();
    #pragma unroll
    for (int ks = 0; ks < 4; ++ks) {
      const int ko = ks * 32;
      short8v afr[4], bfr[4];
      #pragma unroll
      for (int mi = 0; mi < 4; ++mi) {
        const int e = w * 64 + mi * 16 + lr;
        const unsigned int sw = (unsigned)(e & 7) << 4;
        const unsigned char* base = lds_w + e * 256;
        short4v lo = *(const short4v*)(base + (((unsigned)((ko + 4 * g) * 2)) ^ sw));
        short4v hi = *(const short4v*)(base + (((unsigned)((ko + 16 + 4 * g) * 2)) ^ sw));
        afr[mi] = __builtin_shufflevector(lo, hi, 0, 1, 2, 3, 4, 5, 6, 7);
      }
      #pragma unroll
      for (int ni = 0; ni < 4; ++ni) {
        const int rrow = ni * 16 + lr;
        const unsigned int sw = (unsigned)(rrow & 7) << 4;
        const unsigned char* base = lds_cmb + rrow * (KDIM * 2);
        const int kk = k0 + ko;
        short4v lo = *(const short4v*)(base + (((unsigned)((kk + 4 * g) * 2)) ^ sw));
        short4v hi = *(const short4v*)(base + (((unsigned)((kk + 16 + 4 * g) * 2)) ^ sw));
        bfr[ni] = __builtin_shufflevector(lo, hi, 0, 1, 2, 3, 4, 5, 6, 7);
      }
      #pragma unroll
      for (int mi = 0; mi < 4; ++mi)
        #pragma unroll
        for (int ni = 0; ni < 4; ++ni)
          acc[mi][ni] = __builtin_amdgcn_mfma_f32_16x16x32_bf16(afr[mi], bfr[ni], acc[mi][ni], 0, 0, 0);
    }
  }

  #pragma unroll
  for (int ni = 0; ni < 4; ++ni) {
    const int b = b0 + ni * 16 + lr;
    if (b >= B_TOTAL) continue;
    #pragma unroll
    for (int mi = 0; mi < 4; ++mi) {
      const int e = w * 64 + mi * 16 + g * 4;
      #pragma unroll
      for (int q = 0; q < 4; ++q) {
        float v = acc[mi][ni][q];
        out[(size_t)(e + q) * B_TOTAL + b] = v > 0.f ? v : 0.f;
      }
    }
  }
}

extern "C" void kernel_launch(void* const* d_in, const int* in_sizes, int n_in,
                              void* d_out, int out_size, void* d_ws, size_t ws_size,
                              hipStream_t stream) {
  const int*   nodes    = (const int*)d_in[0];
  const int*   neigh    = (const int*)d_in[1];
  const float* features = (const float*)d_in[2];
  const float* weight   = (const float*)d_in[3];
  float*       out      = (float*)d_out;

  if (ws_size >= F8_OFF + F8_SZ) {
    unsigned char* ximg = (unsigned char*)d_ws;
    unsigned char* wimg = (unsigned char*)d_ws + WIMG_OFF;
    unsigned char* f8   = (unsigned char*)d_ws + F8_OFF;
    fp8_pack<<<(N_NODES * FDIM / 8 + 255) / 256, 256, 0, stream>>>(features, f8);
    pack_w<<<128, 256, 0, stream>>>(weight, wimg);
    gather_mean_f8<<<B_PAD / 4, 256, 0, stream>>>(nodes, neigh, features, f8, ximg);
    gemm_relu<<<NBLK, 256, 0, stream>>>(ximg, wimg, out);
  } else {
    encoder_fused<<<(B_TOTAL + 63) / 64, 256, 0, stream>>>(nodes, neigh, features, weight, out);
  }
}